// Round 3
// baseline (123.752 us; speedup 1.0000x reference)
//
#include <hip/hip_runtime.h>
#include <cstdint>

// Lukasiewicz max-plus matmul: y[n,o] = max(b[o], max(0, max_i(x[n,i]+a[o,i]-1)))
// N=2048, K=512, OUT=512, fp32.
//
// R3: LDS-free. R2 counters proved LDS-BW-bound (VALUBusy 34% == 1/3, LDS
// demand:VALU = 3:1). New structure: lane = output col; A streamed to VGPRs
// via coalesced loads from pre-transposed Ap[k4][col][4] in d_ws; X (uniform
// across lanes) via scalar cache (s_load) directly into SGPR operands.
// acc[8 rows]/thread, no K-split, plain coalesced stores.

#define NROW 2048
#define NK   512
#define NCOL 512
#define RP   8                    // rows per block
typedef float f32x4 __attribute__((ext_vector_type(4)));

// ---- prep: Ap4[k4*512 + col] = {A[col][4k4+0..3]} -------------------------
__global__ __launch_bounds__(256) void luka_prep(const float* __restrict__ A,
                                                 f32x4* __restrict__ Ap4) {
  int idx = blockIdx.x * 256 + threadIdx.x;  // 512 cols * 128 k4 = 65536
  int o  = idx >> 7;
  int k4 = idx & 127;
  f32x4 v = *(const f32x4*)(A + o * NK + k4 * 4);  // coalesced read along k
  Ap4[k4 * NCOL + o] = v;                          // 16B scattered write (1MB once)
}

// ---- main -----------------------------------------------------------------
__global__ __launch_bounds__(256) void luka_main(
    const f32x4* __restrict__ Ap4, const float* __restrict__ X,
    const float* __restrict__ Bv, float* __restrict__ Y) {
  const int col  = blockIdx.y * 256 + threadIdx.x;  // lane-distinct col
  const int row0 = blockIdx.x * RP;                 // uniform row panel

  float acc[RP];
#pragma unroll
  for (int r = 0; r < RP; ++r) acc[r] = 0.0f;  // safe: x+a >= 0

  // A double-buffered in VGPRs, 16 k per step (4 x f32x4).
  f32x4 a[4], an[4];
#pragma unroll
  for (int j = 0; j < 4; ++j) a[j] = Ap4[j * NCOL + col];

#pragma unroll 2
  for (int k4 = 0; k4 < NK / 4; k4 += 4) {
    if (k4 + 4 < NK / 4) {
#pragma unroll
      for (int j = 0; j < 4; ++j) an[j] = Ap4[(k4 + 4 + j) * NCOL + col];
    }
#pragma unroll
    for (int r = 0; r < RP; ++r) {
      const float* xp = X + (size_t)(row0 + r) * NK + k4 * 4;  // uniform addr
#pragma unroll
      for (int j = 0; j < 4; ++j) {
        f32x4 xv = *(const f32x4*)(xp + 4 * j);  // uniform -> s_load (SGPRs)
        f32x4 s  = a[j] + xv;                    // 2x v_pk_add_f32
        float t  = fmaxf(fmaxf(s.z, s.w), acc[r]);  // v_max3_f32
        acc[r]   = fmaxf(fmaxf(s.x, s.y), t);       // v_max3_f32
      }
    }
#pragma unroll
    for (int j = 0; j < 4; ++j) a[j] = an[j];  // unroll-2 makes this a rename
  }

  // y = max3(acc - 1, b, 0); exact: max-then-sub == ref's sub-then-max
  // (rounding is monotone, same argmax).
  const float bv = Bv[col];
#pragma unroll
  for (int r = 0; r < RP; ++r) {
    float t = acc[r] - 1.0f;
    Y[(size_t)(row0 + r) * NCOL + col] = fmaxf(fmaxf(t, bv), 0.0f);  // v_max3
  }
}

// ---- fallback (R1 kernel, used only if d_ws < 1MB) ------------------------
#define TILE 64
#define BK   64
__device__ __forceinline__ void async_load16(const float* g, float* l) {
  __builtin_amdgcn_global_load_lds(
      (const __attribute__((address_space(1))) void*)g,
      (__attribute__((address_space(3))) void*)l, 16, 0, 0);
}
__global__ __launch_bounds__(256) void luka_fb(
    const float* __restrict__ X, const float* __restrict__ A,
    const float* __restrict__ Bv, float* __restrict__ Y) {
  __shared__ float xs[2][TILE * BK];
  __shared__ float as[2][TILE * BK];
  const int tid = threadIdx.x, wave = tid >> 6, tx = tid & 15, ty = tid >> 4;
  const int rowBase = blockIdx.y * TILE, colBase = blockIdx.x * TILE;
  uint32_t xoff[4], aoff[4];
#pragma unroll
  for (int r = 0; r < 4; ++r) {
    int row = ty * 4 + r;
    xoff[r] = (uint32_t)row * 256u + ((uint32_t)((row & 15) ^ (row >> 2)) << 4);
  }
#pragma unroll
  for (int c = 0; c < 4; ++c) {
    int row = tx * 4 + c;
    aoff[c] = (uint32_t)row * 256u + ((uint32_t)((row & 15) ^ (row >> 2)) << 4);
  }
  float acc[4][4];
#pragma unroll
  for (int r = 0; r < 4; ++r)
#pragma unroll
    for (int c = 0; c < 4; ++c) acc[r][c] = 0.0f;
  const int row0 = tid >> 4, sl = tid & 15;
  auto stage = [&](int buf, int kt) {
#pragma unroll
    for (int j = 0; j < 4; ++j) {
      int row = row0 + j * 16;
      int m = (row & 15) ^ (row >> 2);
      int kk = ((sl ^ m) << 2);
      async_load16(X + (size_t)(rowBase + row) * NK + kt * BK + kk,
                   &xs[buf][j * 1024 + wave * 256]);
      async_load16(A + (size_t)(colBase + row) * NK + kt * BK + kk,
                   &as[buf][j * 1024 + wave * 256]);
    }
  };
  stage(0, 0);
  __syncthreads();
  int buf = 0;
#pragma unroll 1
  for (int kt = 0; kt < NK / BK; ++kt) {
    if (kt < NK / BK - 1) stage(buf ^ 1, kt + 1);
    const char* xb = (const char*)&xs[buf][0];
    const char* ab = (const char*)&as[buf][0];
#pragma unroll
    for (int s4 = 0; s4 < BK / 4; ++s4) {
      f32x4 xf[4], af[4];
#pragma unroll
      for (int r = 0; r < 4; ++r)
        xf[r] = *(const f32x4*)(xb + (xoff[r] ^ (uint32_t)(s4 << 4)));
#pragma unroll
      for (int c = 0; c < 4; ++c)
        af[c] = *(const f32x4*)(ab + (aoff[c] ^ (uint32_t)(s4 << 4)));
#pragma unroll
      for (int r = 0; r < 4; ++r)
#pragma unroll
        for (int c = 0; c < 4; ++c) {
          f32x4 s = xf[r] + af[c];
          float t0 = fmaxf(fmaxf(s.x, s.y), acc[r][c]);
          acc[r][c] = fmaxf(fmaxf(s.z, s.w), t0);
        }
    }
    __syncthreads();
    buf ^= 1;
  }
  const f32x4 bv = *(const f32x4*)&Bv[colBase + tx * 4];
  float bvv[4] = {bv.x, bv.y, bv.z, bv.w};
#pragma unroll
  for (int r = 0; r < 4; ++r) {
    f32x4 o;
    o.x = fmaxf(fmaxf(acc[r][0] - 1.0f, bvv[0]), 0.0f);
    o.y = fmaxf(fmaxf(acc[r][1] - 1.0f, bvv[1]), 0.0f);
    o.z = fmaxf(fmaxf(acc[r][2] - 1.0f, bvv[2]), 0.0f);
    o.w = fmaxf(fmaxf(acc[r][3] - 1.0f, bvv[3]), 0.0f);
    *(f32x4*)&Y[(size_t)(rowBase + ty * 4 + r) * NCOL + colBase + tx * 4] = o;
  }
}

extern "C" void kernel_launch(void* const* d_in, const int* in_sizes, int n_in,
                              void* d_out, int out_size, void* d_ws, size_t ws_size,
                              hipStream_t stream) {
  const float* X = (const float*)d_in[0];   // [2048][512]
  const float* A = (const float*)d_in[1];   // [512][512]
  const float* B = (const float*)d_in[2];   // [512]
  float* Y = (float*)d_out;                 // [2048][512]

  if (ws_size >= (size_t)NCOL * NK * sizeof(float)) {
    f32x4* Ap4 = (f32x4*)d_ws;
    luka_prep<<<dim3(NCOL * NK / 4 / 256), dim3(256), 0, stream>>>(A, Ap4);
    dim3 grid(NROW / RP, NCOL / 256);       // (256, 2) = 512 blocks
    luka_main<<<grid, dim3(256), 0, stream>>>(Ap4, X, B, Y);
  } else {
    dim3 grid(NCOL / TILE, NROW / TILE);    // fallback: R1 kernel
    luka_fb<<<grid, dim3(256), 0, stream>>>(X, A, B, Y);
  }
}